// Round 8
// baseline (1380.003 us; speedup 1.0000x reference)
//
#include <hip/hip_runtime.h>
#include <hip/hip_bf16.h>

// Problem constants
#define B_SZ 2
#define LSEQ 1024
#define DIN  2048
#define DST  16
#define DTR  64
#define KTOT 96              // DTR + 2*DST
#define NROW (B_SZ * LSEQ)   // 2048 (b,l) rows
#define NCH  64              // number of L-chunks
#define TCH  16              // timesteps per chunk (LSEQ / NCH)
#define KSP  16              // K-splits in k_proj (128 K each)
#define NCHAINS 16           // B_SZ * (DIN/256) independent scan chains

// bf16 (as ushort) -> float
__device__ __forceinline__ float b2f(unsigned int u) {
    union { unsigned int i; float f; } v;
    v.i = (u & 0xffffu) << 16;
    return v.f;
}

// scalar load: element i of a buffer that is either fp32 or bf16
__device__ __forceinline__ float ldf(const void* p, size_t i, bool f32) {
    return f32 ? ((const float*)p)[i] : b2f(((const unsigned short*)p)[i]);
}

// 4 consecutive elements as float4, dual dtype
__device__ __forceinline__ float4 ld4(const void* p, size_t i, bool f32) {
    if (f32) return *(const float4*)((const float*)p + i);
    const uint2 u = *(const uint2*)((const unsigned short*)p + i);
    float4 v;
    v.x = b2f(u.x); v.y = b2f(u.x >> 16);
    v.z = b2f(u.y); v.w = b2f(u.y >> 16);
    return v;
}

__device__ __forceinline__ float softplus_f(float v) {
    return (v > 20.f) ? v : log1pf(__expf(v));
}

// ---------------------------------------------------------------------------
// Kernel 0: dtype detector + zero-init of lookback ticket & flags.
// flag=1 -> fp32, flag=0 -> bf16.
// ---------------------------------------------------------------------------
__global__ __launch_bounds__(256) void k_detect(const void* __restrict__ x,
                                                int* __restrict__ flag,
                                                int* __restrict__ tick,
                                                int* __restrict__ cflags) {
    __shared__ int cnt;
    if (threadIdx.x == 0) { cnt = 0; *tick = 0; }
    for (int i = threadIdx.x; i < NCHAINS * NCH; i += 256) cflags[i] = 0;
    __syncthreads();
    const unsigned short* u = (const unsigned short*)x;
    int my = 0;
    for (int i = threadIdx.x; i < 4096; i += 256) {
        unsigned short v = u[2 * i];
        float af = fabsf(b2f(v));
        if (v == 0 || (af >= 6.0e-8f && af <= 1.7e7f)) my++;
    }
    atomicAdd(&cnt, my);
    __syncthreads();
    if (threadIdx.x == 0) *flag = (cnt < 2048) ? 1 : 0;
}

// ---------------------------------------------------------------------------
// Kernel 1: input projection, tiled split-K GEMM (proven in r6/r7).
// ---------------------------------------------------------------------------
__global__ __launch_bounds__(256, 4) void k_proj(
    const void* __restrict__ x,      // [NROW][DIN]
    const void* __restrict__ Wx,     // [96][DIN]
    const int*  __restrict__ flag,
    float* __restrict__ part)        // [KSP][NROW][96]
{
    const bool f32 = (*flag != 0);
    __shared__ float lx[32][68];     // [k][row], padded
    __shared__ float lw[32][100];    // [k][col], padded
    const int tid = threadIdx.x;
    const int bx = blockIdx.x;       // row group (64 rows)
    const int by = blockIdx.y;       // K-split (128 K)
    const int rt = tid >> 4, ct = tid & 15;
    const int r0 = rt * 4, c0 = ct * 6;

    float acc[4][6];
    #pragma unroll
    for (int i = 0; i < 4; i++)
        #pragma unroll
        for (int k = 0; k < 6; k++) acc[i][k] = 0.f;

    for (int sub = 0; sub < 4; sub++) {
        const int k0 = by * 128 + sub * 32;
        #pragma unroll
        for (int it = 0; it < 2; it++) {
            const int idx = tid + it * 256;
            const int r = idx >> 3, q = idx & 7;
            float4 v = ld4(x, (size_t)(bx * 64 + r) * DIN + k0 + q * 4, f32);
            lx[q * 4 + 0][r] = v.x; lx[q * 4 + 1][r] = v.y;
            lx[q * 4 + 2][r] = v.z; lx[q * 4 + 3][r] = v.w;
        }
        #pragma unroll
        for (int it = 0; it < 3; it++) {
            const int idx = tid + it * 256;
            const int c = idx >> 3, q = idx & 7;
            float4 v = ld4(Wx, (size_t)c * DIN + k0 + q * 4, f32);
            lw[q * 4 + 0][c] = v.x; lw[q * 4 + 1][c] = v.y;
            lw[q * 4 + 2][c] = v.z; lw[q * 4 + 3][c] = v.w;
        }
        __syncthreads();

        #pragma unroll 4
        for (int j = 0; j < 32; j++) {
            const float4 xa = *(const float4*)&lx[j][r0];
            const float2 w0 = *(const float2*)&lw[j][c0];
            const float2 w1 = *(const float2*)&lw[j][c0 + 2];
            const float2 w2 = *(const float2*)&lw[j][c0 + 4];
            const float xr[4] = {xa.x, xa.y, xa.z, xa.w};
            const float wc[6] = {w0.x, w0.y, w1.x, w1.y, w2.x, w2.y};
            #pragma unroll
            for (int i = 0; i < 4; i++)
                #pragma unroll
                for (int k = 0; k < 6; k++)
                    acc[i][k] += xr[i] * wc[k];
        }
        __syncthreads();
    }

    float* p = part + ((size_t)by * NROW + bx * 64 + r0) * KTOT + c0;
    #pragma unroll
    for (int i = 0; i < 4; i++) {
        float* row = p + (size_t)i * KTOT;
        *(float2*)(row)     = make_float2(acc[i][0], acc[i][1]);
        *(float2*)(row + 2) = make_float2(acc[i][2], acc[i][3]);
        *(float2*)(row + 4) = make_float2(acc[i][4], acc[i][5]);
    }
}

// ---------------------------------------------------------------------------
// Kernel 2: combine K-split partials -> drw / Bin / Cin; precompute Aneg.
// ---------------------------------------------------------------------------
__global__ __launch_bounds__(256, 4) void k_comb(
    const float* __restrict__ part,
    const void* __restrict__ Alog,
    const int*  __restrict__ flag,
    float* __restrict__ drw, float* __restrict__ Bin, float* __restrict__ Cin,
    float* __restrict__ Aneg)        // [DIN][DST]
{
    const int idx = blockIdx.x * 256 + threadIdx.x;   // < NROW*96
    float s = 0.f;
    #pragma unroll 8
    for (int ks = 0; ks < KSP; ks++)
        s += part[(size_t)ks * NROW * KTOT + idx];
    const int r = idx / KTOT, c = idx % KTOT;
    if (c < DTR)            drw[r * DTR + c] = s;
    else if (c < DTR + DST) Bin[r * DST + (c - DTR)] = s;
    else                    Cin[r * DST + (c - DTR - DST)] = s;

    if (idx < DST * DIN) {
        const bool f32 = (*flag != 0);
        Aneg[idx] = -__expf(ldf(Alog, (size_t)idx, f32));
    }
}

// ---------------------------------------------------------------------------
// Kernel 3: dt GEMM + softplus (proven tile; kept separate — fusing the K=64
// GEMM into the scan blew registers in round 4).
// ---------------------------------------------------------------------------
__global__ __launch_bounds__(256, 4) void k_dt(
    const float* __restrict__ drw,   // [NROW][DTR]
    const void* __restrict__ Wdt,    // [DIN][DTR]
    const void* __restrict__ bdt,    // [DIN]
    const int*  __restrict__ flag,
    float* __restrict__ dt)          // [NROW][DIN]
{
    const bool f32 = (*flag != 0);
    __shared__ float la[64][68];
    __shared__ float lb[64][68];
    const int tid = threadIdx.x;
    const int r0g = blockIdx.x * 64, c0g = blockIdx.y * 64;

    #pragma unroll
    for (int it = 0; it < 4; it++) {
        const int idx = tid + it * 256;
        const int r = idx >> 4, q = idx & 15;
        float4 v = *(const float4*)(drw + (size_t)(r0g + r) * DTR + q * 4);
        la[q * 4 + 0][r] = v.x; la[q * 4 + 1][r] = v.y;
        la[q * 4 + 2][r] = v.z; la[q * 4 + 3][r] = v.w;
    }
    #pragma unroll
    for (int it = 0; it < 4; it++) {
        const int idx = tid + it * 256;
        const int c = idx >> 4, q = idx & 15;
        float4 v = ld4(Wdt, (size_t)(c0g + c) * DTR + q * 4, f32);
        lb[q * 4 + 0][c] = v.x; lb[q * 4 + 1][c] = v.y;
        lb[q * 4 + 2][c] = v.z; lb[q * 4 + 3][c] = v.w;
    }
    __syncthreads();

    const int rt = tid >> 4, ct = tid & 15;
    const int r0 = rt * 4, c0 = ct * 4;
    float acc[4][4];
    #pragma unroll
    for (int i = 0; i < 4; i++)
        #pragma unroll
        for (int k = 0; k < 4; k++) acc[i][k] = 0.f;

    #pragma unroll 8
    for (int j = 0; j < 64; j++) {
        const float4 a = *(const float4*)&la[j][r0];
        const float4 b = *(const float4*)&lb[j][c0];
        const float ar[4] = {a.x, a.y, a.z, a.w};
        const float bc[4] = {b.x, b.y, b.z, b.w};
        #pragma unroll
        for (int i = 0; i < 4; i++)
            #pragma unroll
            for (int k = 0; k < 4; k++)
                acc[i][k] += ar[i] * bc[k];
    }

    float bd[4];
    #pragma unroll
    for (int k = 0; k < 4; k++) bd[k] = ldf(bdt, (size_t)(c0g + c0 + k), f32);
    #pragma unroll
    for (int i = 0; i < 4; i++) {
        float4 o;
        o.x = softplus_f(acc[i][0] + bd[0]);
        o.y = softplus_f(acc[i][1] + bd[1]);
        o.z = softplus_f(acc[i][2] + bd[2]);
        o.w = softplus_f(acc[i][3] + bd[3]);
        *(float4*)(dt + (size_t)(r0g + r0 + i) * DIN + c0g + c0) = o;
    }
}

// ---------------------------------------------------------------------------
// Kernel 4: FUSED scan (scan1+scan2+scan3) via ticket-ordered decoupled
// lookback. Grid = NCHAINS*NCH flat blocks; each block takes a ticket:
// chain = ticket % 16 (b*8+dblock), c = ticket / 16. Ticket order guarantees
// every block waits only on earlier-ticketed (already started) blocks.
// ---------------------------------------------------------------------------
__global__ __launch_bounds__(256, 3) void k_scanF(
    const void* __restrict__ x,
    const float* __restrict__ dtg,   // [NROW][DIN]
    const float* __restrict__ Bin,
    const float* __restrict__ Cin,
    const float* __restrict__ Aneg,  // [DIN][DST]
    const void* __restrict__ Dv,
    const int*  __restrict__ flag,
    int* tick, int* cflags,          // [NCHAINS][NCH]
    float* Ploc, float* Hloc, float* Hinc,  // [NCHAINS][NCH][DST][256]
    void* __restrict__ y)
{
    __shared__ int s_tick, s_flag;
    __shared__ float Bs[TCH * DST];
    __shared__ float Cs[TCH * DST];
    const int tid = threadIdx.x;
    if (tid == 0) s_tick = atomicAdd(tick, 1);
    __syncthreads();
    const int ticket = s_tick;
    const int chain = ticket & (NCHAINS - 1);
    const int c     = ticket >> 4;           // 0..NCH-1
    const int b = chain >> 3, dblock = chain & 7;
    const int d = dblock * 256 + tid;
    const int row0 = b * LSEQ + c * TCH;
    const bool f32 = (*flag != 0);

    Bs[tid] = Bin[(size_t)row0 * DST + tid];   // TCH*DST == 256 == blockDim
    Cs[tid] = Cin[(size_t)row0 * DST + tid];

    float A[DST];
    #pragma unroll
    for (int sq = 0; sq < 4; sq++)
        *(float4*)(A + sq * 4) = *(const float4*)(Aneg + (size_t)d * DST + sq * 4);
    __syncthreads();

    // load dt + x chunk columns into registers (kept across both passes)
    float dtv[TCH], xv[TCH];
    #pragma unroll
    for (int t = 0; t < TCH; t++) {
        const size_t off = (size_t)(row0 + t) * DIN + d;
        dtv[t] = dtg[off];
        xv[t]  = ldf(x, off, f32);
    }

    // ---- pass 1: local scan, h0 = 0 ----
    float P[DST], H[DST];
    #pragma unroll
    for (int s = 0; s < DST; s++) { P[s] = 1.f; H[s] = 0.f; }

    #pragma unroll 4
    for (int t = 0; t < TCH; t++) {
        const float u = dtv[t] * xv[t];
        const float dtt = dtv[t];
        #pragma unroll
        for (int sq = 0; sq < 4; sq++) {
            const float4 bq = *(const float4*)&Bs[t * DST + sq * 4];
            const float bb[4] = {bq.x, bq.y, bq.z, bq.w};
            #pragma unroll
            for (int r = 0; r < 4; r++) {
                const int s = sq * 4 + r;
                const float e = __expf(dtt * A[s]);
                P[s] *= e;
                H[s] = e * H[s] + u * bb[r];
            }
        }
    }

    const size_t pidx = ((size_t)chain * NCH + c) * (DST * 256) + tid;
    float hin[DST];

    if (c == 0) {
        #pragma unroll
        for (int s = 0; s < DST; s++) {
            hin[s] = 0.f;
            Hinc[pidx + (size_t)s * 256] = H[s];   // inclusive == local
        }
        __threadfence();
        __syncthreads();
        if (tid == 0)
            __hip_atomic_store(&cflags[chain * NCH + 0], 2,
                               __ATOMIC_RELEASE, __HIP_MEMORY_SCOPE_AGENT);
    } else {
        // publish local (P,H), flag=1
        #pragma unroll
        for (int s = 0; s < DST; s++) {
            Ploc[pidx + (size_t)s * 256] = P[s];
            Hloc[pidx + (size_t)s * 256] = H[s];
        }
        __threadfence();
        __syncthreads();
        if (tid == 0)
            __hip_atomic_store(&cflags[chain * NCH + c], 1,
                               __ATOMIC_RELEASE, __HIP_MEMORY_SCOPE_AGENT);

        // lookback
        float carry[DST];
        #pragma unroll
        for (int s = 0; s < DST; s++) { carry[s] = 1.f; hin[s] = 0.f; }
        int j = c - 1;
        while (true) {
            if (tid == 0) {
                int f;
                do {
                    f = __hip_atomic_load(&cflags[chain * NCH + j],
                                          __ATOMIC_ACQUIRE, __HIP_MEMORY_SCOPE_AGENT);
                    if (f == 0) __builtin_amdgcn_s_sleep(8);
                } while (f == 0);
                s_flag = f;
            }
            __syncthreads();
            __threadfence();   // acquire for all threads (invalidate caches)
            const int f = s_flag;
            const size_t jb = ((size_t)chain * NCH + j) * (DST * 256) + tid;
            if (f == 2) {
                #pragma unroll
                for (int s = 0; s < DST; s++)
                    hin[s] += carry[s] * Hinc[jb + (size_t)s * 256];
                break;
            } else {
                #pragma unroll
                for (int s = 0; s < DST; s++) {
                    hin[s]  += carry[s] * Hloc[jb + (size_t)s * 256];
                    carry[s] *= Ploc[jb + (size_t)s * 256];
                }
                j--;
                if (j < 0) break;   // unreachable: chunk 0 publishes flag=2
            }
            __syncthreads();        // keep s_flag writes race-free across iters
        }

        if (c < NCH - 1) {
            #pragma unroll
            for (int s = 0; s < DST; s++)
                Hinc[pidx + (size_t)s * 256] = H[s] + P[s] * hin[s];
            __threadfence();
            __syncthreads();
            if (tid == 0)
                __hip_atomic_store(&cflags[chain * NCH + c], 2,
                                   __ATOMIC_RELEASE, __HIP_MEMORY_SCOPE_AGENT);
        }
    }

    // ---- pass 2: seeded scan, emit y ----
    const float Dd = ldf(Dv, (size_t)d, f32);
    float h[DST];
    #pragma unroll
    for (int s = 0; s < DST; s++) h[s] = hin[s];

    #pragma unroll 4
    for (int t = 0; t < TCH; t++) {
        const float u = dtv[t] * xv[t];
        const float dtt = dtv[t];
        float yv = Dd * xv[t];
        #pragma unroll
        for (int sq = 0; sq < 4; sq++) {
            const float4 bq = *(const float4*)&Bs[t * DST + sq * 4];
            const float4 cq = *(const float4*)&Cs[t * DST + sq * 4];
            const float bb[4] = {bq.x, bq.y, bq.z, bq.w};
            const float cc[4] = {cq.x, cq.y, cq.z, cq.w};
            #pragma unroll
            for (int r = 0; r < 4; r++) {
                const int s = sq * 4 + r;
                const float e = __expf(dtt * A[s]);
                h[s] = e * h[s] + u * bb[r];
                yv += h[s] * cc[r];
            }
        }
        const size_t off = (size_t)(row0 + t) * DIN + d;
        if (f32) ((float*)y)[off] = yv;
        else     ((__hip_bfloat16*)y)[off] = __float2bfloat16(yv);
    }
}

// ---------------------------------------------------------------------------
extern "C" void kernel_launch(void* const* d_in, const int* in_sizes, int n_in,
                              void* d_out, int out_size, void* d_ws, size_t ws_size,
                              hipStream_t stream) {
    const void* x    = d_in[0];
    const void* Wx   = d_in[1];
    const void* Wdt  = d_in[2];
    const void* bdt  = d_in[3];
    const void* Alog = d_in[4];
    const void* Dv   = d_in[5];

    // ---- workspace layout (~82 MB; ws >= 268 MB) ----
    int*   flag   = (int*)d_ws;            // [0]
    int*   tick   = (int*)d_ws + 1;        // [1]
    int*   cflags = (int*)d_ws + 16;       // NCHAINS*NCH = 1024 ints
    float* basep  = (float*)d_ws + 16 + NCHAINS * NCH;  // 16-B aligned
    float* drw  = basep;                                  // NROW*DTR    = 131072
    float* Bin  = drw  + (size_t)NROW * DTR;              // NROW*DST
    float* Cin  = Bin  + (size_t)NROW * DST;              // NROW*DST
    float* Aneg = Cin  + (size_t)NROW * DST;              // DIN*DST
    float* part = Aneg + (size_t)DIN * DST;               // KSP*NROW*96 = 3145728
    float* dt   = part + (size_t)KSP * NROW * KTOT;       // NROW*DIN    = 4194304
    float* Ploc = dt   + (size_t)NROW * DIN;              // 16*64*16*256 = 4194304
    float* Hloc = Ploc + (size_t)NCHAINS * NCH * DST * 256;
    float* Hinc = Hloc + (size_t)NCHAINS * NCH * DST * 256;

    k_detect<<<1, 256, 0, stream>>>(x, flag, tick, cflags);

    k_proj<<<dim3(NROW / 64, KSP), 256, 0, stream>>>(x, Wx, flag, part);

    k_comb<<<(NROW * KTOT) / 256, 256, 0, stream>>>(part, Alog, flag,
                                                    drw, Bin, Cin, Aneg);

    k_dt<<<dim3(NROW / 64, DIN / 64), 256, 0, stream>>>(drw, Wdt, bdt, flag, dt);

    k_scanF<<<NCHAINS * NCH, 256, 0, stream>>>(x, dt, Bin, Cin, Aneg, Dv, flag,
                                               tick, cflags, Ploc, Hloc, Hinc,
                                               d_out);
}

// Round 10
// 473.373 us; speedup vs baseline: 2.9153x; 2.9153x over previous
//
#include <hip/hip_runtime.h>
#include <hip/hip_bf16.h>
#include <hip/hip_cooperative_groups.h>

namespace cg = cooperative_groups;

// Problem constants
#define B_SZ 2
#define LSEQ 1024
#define DIN  2048
#define DST  16
#define DTR  64
#define KTOT 96              // DTR + 2*DST
#define NROW (B_SZ * LSEQ)   // 2048 (b,l) rows
#define NCH  32              // number of L-chunks
#define TCH  32              // timesteps per chunk (LSEQ / NCH)
#define KSP  16              // K-splits in proj (128 K each)
#define NCHAINS 16           // B_SZ * (DIN/256)
#define NBLK 512             // cooperative grid: 2 blocks/CU x 256 CU (2x margin)

// bf16 (as ushort) -> float
__device__ __forceinline__ float b2f(unsigned int u) {
    union { unsigned int i; float f; } v;
    v.i = (u & 0xffffu) << 16;
    return v.f;
}

__device__ __forceinline__ float ldf(const void* p, size_t i, bool f32) {
    return f32 ? ((const float*)p)[i] : b2f(((const unsigned short*)p)[i]);
}

__device__ __forceinline__ float4 ld4(const void* p, size_t i, bool f32) {
    if (f32) return *(const float4*)((const float*)p + i);
    const uint2 u = *(const uint2*)((const unsigned short*)p + i);
    float4 v;
    v.x = b2f(u.x); v.y = b2f(u.x >> 16);
    v.z = b2f(u.y); v.w = b2f(u.y >> 16);
    return v;
}

__device__ __forceinline__ float softplus_f(float v) {
    return (v > 20.f) ? v : log1pf(__expf(v));
}

// ===========================================================================
// Phase bodies (shared between the cooperative mega-kernel and the fallback
// standalone kernels — identical math on both paths).
// ===========================================================================

// ---- proj: one 64-row x 96-col x 128-K split-K tile -> part ---------------
__device__ __forceinline__ void phase_proj(
    int bx, int by, int tid, bool f32,
    const void* __restrict__ x, const void* __restrict__ Wx,
    float* __restrict__ part, float* smem)
{
    float* lx = smem;             // [32][68]
    float* lw = smem + 32 * 68;   // [32][100]
    const int rt = tid >> 4, ct = tid & 15;
    const int r0 = rt * 4, c0 = ct * 6;

    float acc[4][6];
    #pragma unroll
    for (int i = 0; i < 4; i++)
        #pragma unroll
        for (int k = 0; k < 6; k++) acc[i][k] = 0.f;

    for (int sub = 0; sub < 4; sub++) {
        const int k0 = by * 128 + sub * 32;
        #pragma unroll
        for (int it = 0; it < 2; it++) {
            const int idx = tid + it * 256;
            const int r = idx >> 3, q = idx & 7;
            float4 v = ld4(x, (size_t)(bx * 64 + r) * DIN + k0 + q * 4, f32);
            lx[(q * 4 + 0) * 68 + r] = v.x; lx[(q * 4 + 1) * 68 + r] = v.y;
            lx[(q * 4 + 2) * 68 + r] = v.z; lx[(q * 4 + 3) * 68 + r] = v.w;
        }
        #pragma unroll
        for (int it = 0; it < 3; it++) {
            const int idx = tid + it * 256;
            const int c = idx >> 3, q = idx & 7;
            float4 v = ld4(Wx, (size_t)c * DIN + k0 + q * 4, f32);
            lw[(q * 4 + 0) * 100 + c] = v.x; lw[(q * 4 + 1) * 100 + c] = v.y;
            lw[(q * 4 + 2) * 100 + c] = v.z; lw[(q * 4 + 3) * 100 + c] = v.w;
        }
        __syncthreads();

        #pragma unroll 4
        for (int j = 0; j < 32; j++) {
            const float4 xa = *(const float4*)&lx[j * 68 + r0];
            const float2 w0 = *(const float2*)&lw[j * 100 + c0];
            const float2 w1 = *(const float2*)&lw[j * 100 + c0 + 2];
            const float2 w2 = *(const float2*)&lw[j * 100 + c0 + 4];
            const float xr[4] = {xa.x, xa.y, xa.z, xa.w};
            const float wc[6] = {w0.x, w0.y, w1.x, w1.y, w2.x, w2.y};
            #pragma unroll
            for (int i = 0; i < 4; i++)
                #pragma unroll
                for (int k = 0; k < 6; k++)
                    acc[i][k] += xr[i] * wc[k];
        }
        __syncthreads();
    }

    float* p = part + ((size_t)by * NROW + bx * 64 + r0) * KTOT + c0;
    #pragma unroll
    for (int i = 0; i < 4; i++) {
        float* row = p + (size_t)i * KTOT;
        *(float2*)(row)     = make_float2(acc[i][0], acc[i][1]);
        *(float2*)(row + 2) = make_float2(acc[i][2], acc[i][3]);
        *(float2*)(row + 4) = make_float2(acc[i][4], acc[i][5]);
    }
}

// ---- comb: one output element g (< NROW*96); also Aneg for g < DST*DIN ----
__device__ __forceinline__ void phase_comb(
    int g, bool f32,
    const float* __restrict__ part, const void* __restrict__ Alog,
    float* __restrict__ drw, float* __restrict__ Bin, float* __restrict__ Cin,
    float* __restrict__ Aneg)
{
    float s = 0.f;
    #pragma unroll 8
    for (int ks = 0; ks < KSP; ks++)
        s += part[(size_t)ks * NROW * KTOT + g];
    const int r = g / KTOT, c = g % KTOT;
    if (c < DTR)            drw[r * DTR + c] = s;
    else if (c < DTR + DST) Bin[r * DST + (c - DTR)] = s;
    else                    Cin[r * DST + (c - DTR - DST)] = s;

    if (g < DST * DIN)
        Aneg[g] = -__expf(ldf(Alog, (size_t)g, f32));
}

// ---- dt GEMM: one 64x64 tile (tile in 0..1023) ----------------------------
__device__ __forceinline__ void phase_dt(
    int tile, int tid, bool f32,
    const float* __restrict__ drw, const void* __restrict__ Wdt,
    const void* __restrict__ bdt, float* __restrict__ dtg, float* smem)
{
    const int r0g = (tile & 31) * 64, c0g = (tile >> 5) * 64;
    float* la = smem;             // [64][68]
    float* lb = smem + 64 * 68;   // [64][68]

    #pragma unroll
    for (int it = 0; it < 4; it++) {
        const int idx = tid + it * 256;
        const int r = idx >> 4, q = idx & 15;
        float4 v = *(const float4*)(drw + (size_t)(r0g + r) * DTR + q * 4);
        la[(q * 4 + 0) * 68 + r] = v.x; la[(q * 4 + 1) * 68 + r] = v.y;
        la[(q * 4 + 2) * 68 + r] = v.z; la[(q * 4 + 3) * 68 + r] = v.w;
    }
    #pragma unroll
    for (int it = 0; it < 4; it++) {
        const int idx = tid + it * 256;
        const int c = idx >> 4, q = idx & 15;
        float4 v = ld4(Wdt, (size_t)(c0g + c) * DTR + q * 4, f32);
        lb[(q * 4 + 0) * 68 + c] = v.x; lb[(q * 4 + 1) * 68 + c] = v.y;
        lb[(q * 4 + 2) * 68 + c] = v.z; lb[(q * 4 + 3) * 68 + c] = v.w;
    }
    __syncthreads();

    const int rt = tid >> 4, ct = tid & 15;
    const int r0 = rt * 4, c0 = ct * 4;
    float acc[4][4];
    #pragma unroll
    for (int i = 0; i < 4; i++)
        #pragma unroll
        for (int k = 0; k < 4; k++) acc[i][k] = 0.f;

    #pragma unroll 8
    for (int j = 0; j < 64; j++) {
        const float4 a = *(const float4*)&la[j * 68 + r0];
        const float4 b = *(const float4*)&lb[j * 68 + c0];
        const float ar[4] = {a.x, a.y, a.z, a.w};
        const float bc[4] = {b.x, b.y, b.z, b.w};
        #pragma unroll
        for (int i = 0; i < 4; i++)
            #pragma unroll
            for (int k = 0; k < 4; k++)
                acc[i][k] += ar[i] * bc[k];
    }

    float bd[4];
    #pragma unroll
    for (int k = 0; k < 4; k++) bd[k] = ldf(bdt, (size_t)(c0g + c0 + k), f32);
    #pragma unroll
    for (int i = 0; i < 4; i++) {
        float4 o;
        o.x = softplus_f(acc[i][0] + bd[0]);
        o.y = softplus_f(acc[i][1] + bd[1]);
        o.z = softplus_f(acc[i][2] + bd[2]);
        o.w = softplus_f(acc[i][3] + bd[3]);
        *(float4*)(dtg + (size_t)(r0g + r0 + i) * DIN + c0g + c0) = o;
    }
    __syncthreads();   // all LDS reads done before caller may restage
}

// ---- scan1: local chunk scan for (chain, c) -------------------------------
__device__ __forceinline__ void phase_scan1(
    int chain, int c, int tid, bool f32,
    const void* __restrict__ x, const float* __restrict__ dtg,
    const float* __restrict__ Bin, const float* __restrict__ Aneg,
    float* __restrict__ Pb, float* __restrict__ Hb, float* smem)
{
    float* Bs = smem;             // TCH*DST = 512 floats
    const int b = chain >> 3, dblock = chain & 7;
    const int d = dblock * 256 + tid;
    const int row0 = b * LSEQ + c * TCH;

    #pragma unroll
    for (int i = 0; i < 2; i++)
        Bs[tid + i * 256] = Bin[(size_t)row0 * DST + tid + i * 256];

    float A[DST];
    #pragma unroll
    for (int sq = 0; sq < 4; sq++)
        *(float4*)(A + sq * 4) = *(const float4*)(Aneg + (size_t)d * DST + sq * 4);
    __syncthreads();

    float P[DST], H[DST];
    #pragma unroll
    for (int s = 0; s < DST; s++) { P[s] = 1.f; H[s] = 0.f; }

    #pragma unroll 4
    for (int t = 0; t < TCH; t++) {
        const size_t off = (size_t)(row0 + t) * DIN + d;
        const float dtt = dtg[off];
        const float u   = dtt * ldf(x, off, f32);
        #pragma unroll
        for (int sq = 0; sq < 4; sq++) {
            const float4 bq = *(const float4*)&Bs[t * DST + sq * 4];
            const float bb[4] = {bq.x, bq.y, bq.z, bq.w};
            #pragma unroll
            for (int r = 0; r < 4; r++) {
                const int s = sq * 4 + r;
                const float e = __expf(dtt * A[s]);
                P[s] *= e;
                H[s] = e * H[s] + u * bb[r];
            }
        }
    }

    const size_t pidx = ((size_t)chain * NCH + c) * (DST * 256) + tid;
    #pragma unroll
    for (int s = 0; s < DST; s++) {
        Pb[pidx + (size_t)s * 256] = P[s];
        Hb[pidx + (size_t)s * 256] = H[s];
    }
}

// ---- scan2: cross-chunk exclusive scan for one sequence seq ---------------
__device__ __forceinline__ void phase_scan2(
    int seq, float* __restrict__ Pb, const float* __restrict__ Hb)
{
    const int ch  = seq >> 12;          // chain
    const int rem = seq & 4095;         // s*256 + dlocal
    float h = 0.f;
    #pragma unroll 8
    for (int cc = 0; cc < NCH; cc++) {
        const size_t o = ((size_t)ch * NCH + cc) * 4096 + rem;
        const float p = Pb[o], hb = Hb[o];
        Pb[o] = h;                      // becomes hin
        h = hb + p * h;
    }
}

// ---- scan3: seeded scan + y emit for (chain, c) ---------------------------
__device__ __forceinline__ void phase_scan3(
    int chain, int c, int tid, bool f32,
    const void* __restrict__ x, const float* __restrict__ dtg,
    const float* __restrict__ Bin, const float* __restrict__ Cin,
    const float* __restrict__ Aneg, const void* __restrict__ Dv,
    const float* __restrict__ hin, void* __restrict__ y, float* smem)
{
    float* Bs = smem;                   // 512
    float* Cs = smem + TCH * DST;       // 512
    const int b = chain >> 3, dblock = chain & 7;
    const int d = dblock * 256 + tid;
    const int row0 = b * LSEQ + c * TCH;

    #pragma unroll
    for (int i = 0; i < 2; i++) {
        Bs[tid + i * 256] = Bin[(size_t)row0 * DST + tid + i * 256];
        Cs[tid + i * 256] = Cin[(size_t)row0 * DST + tid + i * 256];
    }

    float A[DST];
    #pragma unroll
    for (int sq = 0; sq < 4; sq++)
        *(float4*)(A + sq * 4) = *(const float4*)(Aneg + (size_t)d * DST + sq * 4);
    const float Dd = ldf(Dv, (size_t)d, f32);
    __syncthreads();

    float h[DST];
    const size_t pidx = ((size_t)chain * NCH + c) * (DST * 256) + tid;
    #pragma unroll
    for (int s = 0; s < DST; s++) h[s] = hin[pidx + (size_t)s * 256];

    #pragma unroll 4
    for (int t = 0; t < TCH; t++) {
        const size_t off = (size_t)(row0 + t) * DIN + d;
        const float dtt = dtg[off];
        const float xv  = ldf(x, off, f32);
        const float u   = dtt * xv;
        float yv = Dd * xv;
        #pragma unroll
        for (int sq = 0; sq < 4; sq++) {
            const float4 bq = *(const float4*)&Bs[t * DST + sq * 4];
            const float4 cq = *(const float4*)&Cs[t * DST + sq * 4];
            const float bb[4] = {bq.x, bq.y, bq.z, bq.w};
            const float cc[4] = {cq.x, cq.y, cq.z, cq.w};
            #pragma unroll
            for (int r = 0; r < 4; r++) {
                const int s = sq * 4 + r;
                const float e = __expf(dtt * A[s]);
                h[s] = e * h[s] + u * bb[r];
                yv += h[s] * cc[r];
            }
        }
        if (f32) ((float*)y)[off] = yv;
        else     ((__hip_bfloat16*)y)[off] = __float2bfloat16(yv);
    }
}

// ===========================================================================
// Kernels
// ===========================================================================

__global__ __launch_bounds__(256) void k_detect(const void* __restrict__ x,
                                                int* __restrict__ flag) {
    __shared__ int cnt;
    if (threadIdx.x == 0) cnt = 0;
    __syncthreads();
    const unsigned short* u = (const unsigned short*)x;
    int my = 0;
    for (int i = threadIdx.x; i < 4096; i += 256) {
        unsigned short v = u[2 * i];
        float af = fabsf(b2f(v));
        if (v == 0 || (af >= 6.0e-8f && af <= 1.7e7f)) my++;
    }
    atomicAdd(&cnt, my);
    __syncthreads();
    if (threadIdx.x == 0) *flag = (cnt < 2048) ? 1 : 0;
}

// ---- cooperative mega-kernel: all phases, grid.sync() between -------------
__global__ __launch_bounds__(256, 4) void k_mega(
    const void* __restrict__ x, const void* __restrict__ Wx,
    const void* __restrict__ Wdt, const void* __restrict__ bdt,
    const void* __restrict__ Alog, const void* __restrict__ Dv,
    const int* __restrict__ flag,
    float* __restrict__ part, float* __restrict__ drw,
    float* __restrict__ Bin, float* __restrict__ Cin,
    float* __restrict__ Aneg, float* __restrict__ dtg,
    float* __restrict__ Pb, float* __restrict__ Hb,
    void* __restrict__ y)
{
    cg::grid_group grid = cg::this_grid();
    __shared__ float smem[8704];        // 34816 B (dt GEMM union)
    const int tid = threadIdx.x;
    const int bid = blockIdx.x;
    const bool f32 = (*flag != 0);

    // Phase 0: proj — 512 tiles (32 row-groups x 16 K-splits)
    phase_proj(bid & 31, bid >> 5, tid, f32, x, Wx, part, smem);
    grid.sync();

    // Phase 1: combine + Aneg (196608 elements, 131072 threads)
    for (int g = bid * 256 + tid; g < NROW * KTOT; g += NBLK * 256)
        phase_comb(g, f32, part, Alog, drw, Bin, Cin, Aneg);
    grid.sync();

    // Phase 2: dt GEMM — 1024 tiles, 2 per block
    phase_dt(bid, tid, f32, drw, Wdt, bdt, dtg, smem);
    __syncthreads();
    phase_dt(bid + NBLK, tid, f32, drw, Wdt, bdt, dtg, smem);
    grid.sync();

    // Phase 3: local chunk scans — 16 chains x 32 chunks = 512 blocks
    phase_scan1(bid >> 5, bid & 31, tid, f32, x, dtg, Bin, Aneg, Pb, Hb, smem);
    grid.sync();

    // Phase 4: cross-chunk exclusive scan — 65536 sequences
    {
        const int seq = bid * 256 + tid;
        if (seq < NCHAINS * DST * 256) phase_scan2(seq, Pb, Hb);
    }
    grid.sync();

    // Phase 5: seeded scan, emit y
    phase_scan3(bid >> 5, bid & 31, tid, f32, x, dtg, Bin, Cin, Aneg, Dv,
                Pb, y, smem);
}

// ---- fallback standalone kernels (proven round-6 structure) ---------------
__global__ __launch_bounds__(256, 4) void k_proj(
    const void* x, const void* Wx, const int* flag, float* part) {
    __shared__ float smem[5376];
    phase_proj(blockIdx.x, blockIdx.y, threadIdx.x, *flag != 0, x, Wx, part, smem);
}

__global__ __launch_bounds__(256, 4) void k_comb(
    const float* part, const void* Alog, const int* flag,
    float* drw, float* Bin, float* Cin, float* Aneg) {
    const int g = blockIdx.x * 256 + threadIdx.x;
    if (g < NROW * KTOT)
        phase_comb(g, *flag != 0, part, Alog, drw, Bin, Cin, Aneg);
}

__global__ __launch_bounds__(256, 4) void k_dt(
    const float* drw, const void* Wdt, const void* bdt, const int* flag,
    float* dtg) {
    __shared__ float smem[8704];
    phase_dt(blockIdx.x, threadIdx.x, *flag != 0, drw, Wdt, bdt, dtg, smem);
}

__global__ __launch_bounds__(256, 4) void k_scan1(
    const void* x, const float* dtg, const float* Bin, const float* Aneg,
    const int* flag, float* Pb, float* Hb) {
    __shared__ float smem[512];
    phase_scan1(blockIdx.x >> 5, blockIdx.x & 31, threadIdx.x, *flag != 0,
                x, dtg, Bin, Aneg, Pb, Hb, smem);
}

__global__ __launch_bounds__(256, 4) void k_scan2(float* Pb, const float* Hb) {
    phase_scan2(blockIdx.x * 256 + threadIdx.x, Pb, Hb);
}

__global__ __launch_bounds__(256, 4) void k_scan3(
    const void* x, const float* dtg, const float* Bin, const float* Cin,
    const float* Aneg, const void* Dv, const float* hin, const int* flag,
    void* y) {
    __shared__ float smem[1024];
    phase_scan3(blockIdx.x >> 5, blockIdx.x & 31, threadIdx.x, *flag != 0,
                x, dtg, Bin, Cin, Aneg, Dv, hin, y, smem);
}

// ---------------------------------------------------------------------------
extern "C" void kernel_launch(void* const* d_in, const int* in_sizes, int n_in,
                              void* d_out, int out_size, void* d_ws, size_t ws_size,
                              hipStream_t stream) {
    const void* x    = d_in[0];
    const void* Wx   = d_in[1];
    const void* Wdt  = d_in[2];
    const void* bdt  = d_in[3];
    const void* Alog = d_in[4];
    const void* Dv   = d_in[5];
    void* yv = d_out;

    // ---- workspace layout (~47 MB; ws >= 268 MB) ----
    int*   flag  = (int*)d_ws;
    float* basep = (float*)d_ws + 16;
    float* drw  = basep;                                   // NROW*DTR
    float* Bin  = drw  + (size_t)NROW * DTR;
    float* Cin  = Bin  + (size_t)NROW * DST;
    float* Aneg = Cin  + (size_t)NROW * DST;               // DIN*DST
    float* part = Aneg + (size_t)DIN * DST;                // KSP*NROW*96
    float* dt   = part + (size_t)KSP * NROW * KTOT;        // NROW*DIN
    float* Pb   = dt   + (size_t)NROW * DIN;               // 16*NCH*DST*256
    float* Hb   = Pb   + (size_t)NCHAINS * NCH * DST * 256;

    k_detect<<<1, 256, 0, stream>>>(x, flag);

    void* kargs[] = {(void*)&x, (void*)&Wx, (void*)&Wdt, (void*)&bdt,
                     (void*)&Alog, (void*)&Dv, (void*)&flag,
                     (void*)&part, (void*)&drw, (void*)&Bin, (void*)&Cin,
                     (void*)&Aneg, (void*)&dt, (void*)&Pb, (void*)&Hb,
                     (void*)&yv};
    hipError_t err = hipLaunchCooperativeKernel(
        (const void*)k_mega, dim3(NBLK), dim3(256), kargs, 0, stream);

    if (err != hipSuccess) {
        (void)hipGetLastError();   // clear sticky error, run proven fallback
        k_proj <<<dim3(32, KSP), 256, 0, stream>>>(x, Wx, flag, part);
        k_comb <<<(NROW * KTOT) / 256, 256, 0, stream>>>(part, Alog, flag,
                                                         drw, Bin, Cin, Aneg);
        k_dt   <<<1024, 256, 0, stream>>>(drw, Wdt, bdt, flag, dt);
        k_scan1<<<NCHAINS * NCH, 256, 0, stream>>>(x, dt, Bin, Aneg, flag, Pb, Hb);
        k_scan2<<<(NCHAINS * DST * 256) / 256, 256, 0, stream>>>(Pb, Hb);
        k_scan3<<<NCHAINS * NCH, 256, 0, stream>>>(x, dt, Bin, Cin, Aneg, Dv,
                                                   Pb, flag, d_out);
    }
}

// Round 11
// 242.153 us; speedup vs baseline: 5.6989x; 1.9549x over previous
//
#include <hip/hip_runtime.h>
#include <hip/hip_bf16.h>

// Problem constants
#define B_SZ 2
#define LSEQ 1024
#define DIN  2048
#define DST  16
#define DTR  64
#define KTOT 96              // DTR + 2*DST
#define NROW (B_SZ * LSEQ)   // 2048 (b,l) rows
#define NCH  64              // number of L-chunks
#define TCH  16              // timesteps per chunk (LSEQ / NCH)
#define KSP  16              // K-splits in proj (128 K each)
#define NCHAINS 32           // B_SZ * (DIN/128) chains (128-d slices)

// bf16 (as ushort) -> float
__device__ __forceinline__ float b2f(unsigned int u) {
    union { unsigned int i; float f; } v;
    v.i = (u & 0xffffu) << 16;
    return v.f;
}

__device__ __forceinline__ float ldf(const void* p, size_t i, bool f32) {
    return f32 ? ((const float*)p)[i] : b2f(((const unsigned short*)p)[i]);
}

__device__ __forceinline__ float4 ld4(const void* p, size_t i, bool f32) {
    if (f32) return *(const float4*)((const float*)p + i);
    const uint2 u = *(const uint2*)((const unsigned short*)p + i);
    float4 v;
    v.x = b2f(u.x); v.y = b2f(u.x >> 16);
    v.z = b2f(u.y); v.w = b2f(u.y >> 16);
    return v;
}

__device__ __forceinline__ float softplus_f(float v) {
    return (v > 20.f) ? v : log1pf(__expf(v));
}

// ---------------------------------------------------------------------------
// Kernel 0 (prep): per-block dtype detection (no cross-block dep), zero the
// xz accumulator (proj atomicAdds into it), precompute Aneg = -exp(A_log).
// Block 0 also publishes the flag for downstream kernels.
// ---------------------------------------------------------------------------
__global__ __launch_bounds__(256) void k_prep(
    const void* __restrict__ x, const void* __restrict__ Alog,
    int* __restrict__ flag, float* __restrict__ xz, float* __restrict__ Aneg)
{
    __shared__ int cnt;
    if (threadIdx.x == 0) cnt = 0;
    __syncthreads();
    const unsigned short* u = (const unsigned short*)x;
    int my = 0;
    for (int i = threadIdx.x; i < 4096; i += 256) {
        unsigned short v = u[2 * i];
        float af = fabsf(b2f(v));
        if (v == 0 || (af >= 6.0e-8f && af <= 1.7e7f)) my++;
    }
    atomicAdd(&cnt, my);
    __syncthreads();
    const bool f32 = (cnt < 2048);
    if (blockIdx.x == 0 && threadIdx.x == 0) *flag = f32 ? 1 : 0;

    const int g0 = blockIdx.x * 256 + threadIdx.x;
    #pragma unroll
    for (int it = 0; it < 3; it++) {               // 3*65536 = 196608 = NROW*96
        const int g = g0 + it * 65536;
        if (g < NROW * KTOT) xz[g] = 0.f;
    }
    if (g0 < DST * DIN)
        Aneg[g0] = -__expf(ldf(Alog, (size_t)g0, f32));
}

// ---------------------------------------------------------------------------
// Kernel 1: input projection, split-K GEMM, atomicAdd into xz[r][96].
// Tile 64 rows x 96 cols x 128 K; 256 threads, thread-tile 4x6.
// (VGPR discipline per round-5 lesson: bounded unrolls, (256,4) cap.)
// ---------------------------------------------------------------------------
__global__ __launch_bounds__(256, 4) void k_proj(
    const void* __restrict__ x,      // [NROW][DIN]
    const void* __restrict__ Wx,     // [96][DIN]
    const int*  __restrict__ flag,
    float* __restrict__ xz)          // [NROW][96], pre-zeroed
{
    const bool f32 = (*flag != 0);
    __shared__ float lx[32 * 68];    // [k][row]
    __shared__ float lw[32 * 100];   // [k][col]
    const int tid = threadIdx.x;
    const int bx = blockIdx.x;       // row group (64 rows)
    const int by = blockIdx.y;       // K-split (128 K)
    const int rt = tid >> 4, ct = tid & 15;
    const int r0 = rt * 4, c0 = ct * 6;

    float acc[4][6];
    #pragma unroll
    for (int i = 0; i < 4; i++)
        #pragma unroll
        for (int k = 0; k < 6; k++) acc[i][k] = 0.f;

    for (int sub = 0; sub < 4; sub++) {
        const int k0 = by * 128 + sub * 32;
        #pragma unroll
        for (int it = 0; it < 2; it++) {
            const int idx = tid + it * 256;
            const int r = idx >> 3, q = idx & 7;
            float4 v = ld4(x, (size_t)(bx * 64 + r) * DIN + k0 + q * 4, f32);
            lx[(q * 4 + 0) * 68 + r] = v.x; lx[(q * 4 + 1) * 68 + r] = v.y;
            lx[(q * 4 + 2) * 68 + r] = v.z; lx[(q * 4 + 3) * 68 + r] = v.w;
        }
        #pragma unroll
        for (int it = 0; it < 3; it++) {
            const int idx = tid + it * 256;
            const int c = idx >> 3, q = idx & 7;
            float4 v = ld4(Wx, (size_t)c * DIN + k0 + q * 4, f32);
            lw[(q * 4 + 0) * 100 + c] = v.x; lw[(q * 4 + 1) * 100 + c] = v.y;
            lw[(q * 4 + 2) * 100 + c] = v.z; lw[(q * 4 + 3) * 100 + c] = v.w;
        }
        __syncthreads();

        #pragma unroll 4
        for (int j = 0; j < 32; j++) {
            const float4 xa = *(const float4*)&lx[j * 68 + r0];
            const float2 w0 = *(const float2*)&lw[j * 100 + c0];
            const float2 w1 = *(const float2*)&lw[j * 100 + c0 + 2];
            const float2 w2 = *(const float2*)&lw[j * 100 + c0 + 4];
            const float xr[4] = {xa.x, xa.y, xa.z, xa.w};
            const float wc[6] = {w0.x, w0.y, w1.x, w1.y, w2.x, w2.y};
            #pragma unroll
            for (int i = 0; i < 4; i++)
                #pragma unroll
                for (int k = 0; k < 6; k++)
                    acc[i][k] += xr[i] * wc[k];
        }
        __syncthreads();
    }

    // accumulate into xz (16-way contention per address — negligible)
    #pragma unroll
    for (int i = 0; i < 4; i++) {
        float* row = xz + (size_t)(bx * 64 + r0 + i) * KTOT + c0;
        #pragma unroll
        for (int k = 0; k < 6; k++)
            atomicAdd(row + k, acc[i][k]);
    }
}

// ---------------------------------------------------------------------------
// Kernel 2: dt GEMM + softplus. Reads delta_raw rows from xz (stride 96).
// M=2048, N=2048, K=64. Block 256, tile 64x64, thread 4x4 (proven r6).
// ---------------------------------------------------------------------------
__global__ __launch_bounds__(256, 4) void k_dt(
    const float* __restrict__ xz,    // [NROW][96] (first 64 = delta_raw)
    const void* __restrict__ Wdt,    // [DIN][DTR]
    const void* __restrict__ bdt,    // [DIN]
    const int*  __restrict__ flag,
    float* __restrict__ dtg)         // [NROW][DIN]
{
    const bool f32 = (*flag != 0);
    __shared__ float la[64 * 68];
    __shared__ float lb[64 * 68];
    const int tid = threadIdx.x;
    const int r0g = blockIdx.x * 64, c0g = blockIdx.y * 64;

    #pragma unroll
    for (int it = 0; it < 4; it++) {
        const int idx = tid + it * 256;
        const int r = idx >> 4, q = idx & 15;
        float4 v = *(const float4*)(xz + (size_t)(r0g + r) * KTOT + q * 4);
        la[(q * 4 + 0) * 68 + r] = v.x; la[(q * 4 + 1) * 68 + r] = v.y;
        la[(q * 4 + 2) * 68 + r] = v.z; la[(q * 4 + 3) * 68 + r] = v.w;
    }
    #pragma unroll
    for (int it = 0; it < 4; it++) {
        const int idx = tid + it * 256;
        const int c = idx >> 4, q = idx & 15;
        float4 v = ld4(Wdt, (size_t)(c0g + c) * DTR + q * 4, f32);
        lb[(q * 4 + 0) * 68 + c] = v.x; lb[(q * 4 + 1) * 68 + c] = v.y;
        lb[(q * 4 + 2) * 68 + c] = v.z; lb[(q * 4 + 3) * 68 + c] = v.w;
    }
    __syncthreads();

    const int rt = tid >> 4, ct = tid & 15;
    const int r0 = rt * 4, c0 = ct * 4;
    float acc[4][4];
    #pragma unroll
    for (int i = 0; i < 4; i++)
        #pragma unroll
        for (int k = 0; k < 4; k++) acc[i][k] = 0.f;

    #pragma unroll 8
    for (int j = 0; j < 64; j++) {
        const float4 a = *(const float4*)&la[j * 68 + r0];
        const float4 b = *(const float4*)&lb[j * 68 + c0];
        const float ar[4] = {a.x, a.y, a.z, a.w};
        const float bc[4] = {b.x, b.y, b.z, b.w};
        #pragma unroll
        for (int i = 0; i < 4; i++)
            #pragma unroll
            for (int k = 0; k < 4; k++)
                acc[i][k] += ar[i] * bc[k];
    }

    float bd[4];
    #pragma unroll
    for (int k = 0; k < 4; k++) bd[k] = ldf(bdt, (size_t)(c0g + c0 + k), f32);
    #pragma unroll
    for (int i = 0; i < 4; i++) {
        float4 o;
        o.x = softplus_f(acc[i][0] + bd[0]);
        o.y = softplus_f(acc[i][1] + bd[1]);
        o.z = softplus_f(acc[i][2] + bd[2]);
        o.w = softplus_f(acc[i][3] + bd[3]);
        *(float4*)(dtg + (size_t)(r0g + r0 + i) * DIN + c0g + c0) = o;
    }
}

// ---------------------------------------------------------------------------
// Scan kernels, STATE-SPLIT: thread pairs share one d; each thread owns 8 of
// the 16 states. Halved register live-set -> __launch_bounds__(256,8)
// (64-VGPR cap) and 2048-block grids = 8 blocks/CU.
// Block: bid = chain*NCH + c; chain = b*16 + dblk (128-d slices).
// Thread: dlocal = tid>>1 (0..127), shalf = tid&1 (states shalf*8..+8).
// Pb/Hb layout: [chain][c][s(16)][dlocal(128)].
// ---------------------------------------------------------------------------
__global__ __launch_bounds__(256, 8) void k_scan1(
    const void* __restrict__ x,
    const float* __restrict__ dtg,
    const float* __restrict__ xz,    // Bin at [r][96]+64
    const float* __restrict__ Aneg,  // [DIN][DST]
    const int*  __restrict__ flag,
    float* __restrict__ Pb, float* __restrict__ Hb)
{
    const bool f32 = (*flag != 0);
    __shared__ float Bs[TCH * DST];  // 256 floats
    const int tid = threadIdx.x;
    const int bid = blockIdx.x;
    const int chain = bid >> 6, c = bid & 63;
    const int b = chain >> 4, dblk = chain & 15;
    const int dlocal = tid >> 1, shalf = tid & 1;
    const int d = dblk * 128 + dlocal;
    const int row0 = b * LSEQ + c * TCH;

    {   // stage B rows: element tid -> row tid>>4, s tid&15
        const int r = tid >> 4, s = tid & 15;
        Bs[tid] = xz[(size_t)(row0 + r) * KTOT + DTR + s];
    }
    float A[8];
    #pragma unroll
    for (int q = 0; q < 2; q++)
        *(float4*)(A + q * 4) =
            *(const float4*)(Aneg + (size_t)d * DST + shalf * 8 + q * 4);
    __syncthreads();

    float P[8], H[8];
    #pragma unroll
    for (int k = 0; k < 8; k++) { P[k] = 1.f; H[k] = 0.f; }

    #pragma unroll 4
    for (int t = 0; t < TCH; t++) {
        const size_t off = (size_t)(row0 + t) * DIN + d;
        const float dtt = dtg[off];
        const float u   = dtt * ldf(x, off, f32);
        const float* bs = Bs + t * DST + shalf * 8;
        #pragma unroll
        for (int k = 0; k < 8; k++) {
            const float e = __expf(dtt * A[k]);
            P[k] *= e;
            H[k] = e * H[k] + u * bs[k];
        }
    }

    const size_t base = ((size_t)chain * NCH + c) * (DST * 128)
                      + (size_t)shalf * 8 * 128 + dlocal;
    #pragma unroll
    for (int k = 0; k < 8; k++) {
        Pb[base + (size_t)k * 128] = P[k];
        Hb[base + (size_t)k * 128] = H[k];
    }
}

// ---------------------------------------------------------------------------
// Cross-chunk exclusive scan per sequence (chain, s, dlocal). IN-PLACE on Pb.
// ---------------------------------------------------------------------------
__global__ __launch_bounds__(256, 8) void k_scan2(
    float* __restrict__ Pb, const float* __restrict__ Hb)
{
    const int g = blockIdx.x * 256 + threadIdx.x;   // < 32*16*128 = 65536
    const int chain = g >> 11;
    const int rem   = g & 2047;                     // s*128 + dlocal
    float h = 0.f;
    #pragma unroll 8
    for (int cc = 0; cc < NCH; cc++) {
        const size_t o = ((size_t)chain * NCH + cc) * 2048 + rem;
        const float p = Pb[o], hb = Hb[o];
        Pb[o] = h;
        h = hb + p * h;
    }
}

// ---------------------------------------------------------------------------
// Seeded scan + y emit. Pair lanes combine yv via shfl_xor(1).
// ---------------------------------------------------------------------------
__global__ __launch_bounds__(256, 8) void k_scan3(
    const void* __restrict__ x,
    const float* __restrict__ dtg,
    const float* __restrict__ xz,    // Bin/Cin at [r][96]+64/+80
    const float* __restrict__ Aneg,
    const void* __restrict__ Dv,
    const float* __restrict__ hin,   // = Pb after k_scan2
    const int*  __restrict__ flag,
    void* __restrict__ y)
{
    const bool f32 = (*flag != 0);
    __shared__ float Bs[TCH * DST];
    __shared__ float Cs[TCH * DST];
    const int tid = threadIdx.x;
    const int bid = blockIdx.x;
    const int chain = bid >> 6, c = bid & 63;
    const int b = chain >> 4, dblk = chain & 15;
    const int dlocal = tid >> 1, shalf = tid & 1;
    const int d = dblk * 128 + dlocal;
    const int row0 = b * LSEQ + c * TCH;

    {
        const int r = tid >> 4, s = tid & 15;
        Bs[tid] = xz[(size_t)(row0 + r) * KTOT + DTR + s];
        Cs[tid] = xz[(size_t)(row0 + r) * KTOT + DTR + DST + s];
    }
    float A[8];
    #pragma unroll
    for (int q = 0; q < 2; q++)
        *(float4*)(A + q * 4) =
            *(const float4*)(Aneg + (size_t)d * DST + shalf * 8 + q * 4);
    const float Dd = ldf(Dv, (size_t)d, f32);
    __syncthreads();

    float h[8];
    const size_t base = ((size_t)chain * NCH + c) * (DST * 128)
                      + (size_t)shalf * 8 * 128 + dlocal;
    #pragma unroll
    for (int k = 0; k < 8; k++) h[k] = hin[base + (size_t)k * 128];

    #pragma unroll 4
    for (int t = 0; t < TCH; t++) {
        const size_t off = (size_t)(row0 + t) * DIN + d;
        const float dtt = dtg[off];
        const float xv  = ldf(x, off, f32);
        const float u   = dtt * xv;
        const float* bs = Bs + t * DST + shalf * 8;
        const float* cs = Cs + t * DST + shalf * 8;
        float yp = 0.f;
        #pragma unroll
        for (int k = 0; k < 8; k++) {
            const float e = __expf(dtt * A[k]);
            h[k] = e * h[k] + u * bs[k];
            yp += h[k] * cs[k];
        }
        const float ytot = yp + __shfl_xor(yp, 1, 64) + Dd * xv;
        if (shalf == 0) {
            if (f32) ((float*)y)[off] = ytot;
            else     ((__hip_bfloat16*)y)[off] = __float2bfloat16(ytot);
        }
    }
}

// ---------------------------------------------------------------------------
extern "C" void kernel_launch(void* const* d_in, const int* in_sizes, int n_in,
                              void* d_out, int out_size, void* d_ws, size_t ws_size,
                              hipStream_t stream) {
    const void* x    = d_in[0];
    const void* Wx   = d_in[1];
    const void* Wdt  = d_in[2];
    const void* bdt  = d_in[3];
    const void* Alog = d_in[4];
    const void* Dv   = d_in[5];

    // ---- workspace layout (~51 MB; ws >= 268 MB) ----
    int*   flag  = (int*)d_ws;
    float* basep = (float*)d_ws + 16;
    float* xz   = basep;                                   // NROW*96 = 196608
    float* Aneg = xz   + (size_t)NROW * KTOT;              // DIN*DST = 32768
    float* dt   = Aneg + (size_t)DIN * DST;                // NROW*DIN = 4194304
    float* Pb   = dt   + (size_t)NROW * DIN;               // 32*64*16*128 = 4194304
    float* Hb   = Pb   + (size_t)NCHAINS * NCH * DST * 128;

    k_prep<<<256, 256, 0, stream>>>(x, Alog, flag, xz, Aneg);

    k_proj<<<dim3(NROW / 64, KSP), 256, 0, stream>>>(x, Wx, flag, xz);

    k_dt<<<dim3(NROW / 64, DIN / 64), 256, 0, stream>>>(xz, Wdt, bdt, flag, dt);

    k_scan1<<<NCHAINS * NCH, 256, 0, stream>>>(x, dt, xz, Aneg, flag, Pb, Hb);

    k_scan2<<<(NCHAINS * DST * 128) / 256, 256, 0, stream>>>(Pb, Hb);

    k_scan3<<<NCHAINS * NCH, 256, 0, stream>>>(x, dt, xz, Aneg, Dv, Pb, flag,
                                               d_out);
}